// Round 3
// baseline (109.940 us; speedup 1.0000x reference)
//
#include <hip/hip_runtime.h>

// B=128, K=256, M=8, D=128 ; rows = B*K = 32768 flattened (b,k)
#define LT      20.0f
#define LN2     0.69314718055994531f
#define C2EXP   28.853900817779268f   // LT/ln2 : e^(LT*x) = 2^(C2EXP*x)
#define CHUNKS  16                    // 16 chunks x 128 prototype-cols = 2048
#define NBLK    512                   // main grid: 512 blocks x 512 threads
#define PW_COPY 262144                // halves per Pw copy (512 KB / 2B)

typedef _Float16 half8 __attribute__((ext_vector_type(8)));
typedef float    f32x4 __attribute__((ext_vector_type(4)));

#if __has_builtin(__builtin_amdgcn_exp2f)
#define EXP2F(x) __builtin_amdgcn_exp2f(x)
#else
#define EXP2F(x) __expf(0.69314718055994531f * (x))
#endif

__device__ __forceinline__ float swz16(float x) {
    // xor lane^16 within 32-lane halves (BitMode: xor=16, and=0x1F)
    return __int_as_float(__builtin_amdgcn_ds_swizzle(__float_as_int(x), 0x401F));
}

// async global->LDS, 16B per lane; lds base must be wave-uniform
#define GLD16(gp, lp) __builtin_amdgcn_global_load_lds( \
    (const __attribute__((address_space(1))) void*)(gp), \
    (__attribute__((address_space(3))) void*)(lp), 16, 0, 0)

// ---- prep: f32 P -> f16 scaled by C2EXP, packed in fragment lane order,
// REPLICATED 8x so each XCD's L2 gets its own full copy.
// Block g dispatches to XCD g%8 (round-robin) and writes copy g%8 -> the
// copy is produced in the L2 that main blocks with blockIdx%8==g%8 consume.
// Within a copy: half8 slot id = ch*2048 + colq*512 + cfrag*64 + lane
//   c = cfrag&3 (K-slice), h = cfrag>>2 (proto half), n = lane&15, q = lane>>4
//   col = colq*32 + (n>>2)*8 + (n&3) + 4*h ; gcol = ch*128+col ; d = c*32+q*8
__global__ __launch_bounds__(256)
void mpcl_prep(const float* __restrict__ P, _Float16* __restrict__ Pw,
               int* __restrict__ ws)
{
    if (blockIdx.x == 0 && threadIdx.x == 0) ws[0] = 0;   // zero gcnt
    int copy = blockIdx.x & 7;
    int id   = (blockIdx.x >> 3) * 256 + threadIdx.x;     // 0..32767
    int ch    = id >> 11;
    int colq  = (id >> 9) & 3;
    int cfrag = (id >> 6) & 7;
    int lane  = id & 63;
    int n = lane & 15, q = lane >> 4;
    int c = cfrag & 3, h = cfrag >> 2;
    int col  = colq * 32 + ((n >> 2) << 3) + (n & 3) + (h << 2);
    int gcol = (ch << 7) + col;
    const float* src = P + ((size_t)gcol << 7) + c * 32 + q * 8;
    float4 a = *(const float4*)src;
    float4 b = *(const float4*)(src + 4);
    half8 hv;   // pre-scaled: MFMA will emit y = C2EXP * sim directly
    hv[0] = (_Float16)(C2EXP * a.x); hv[1] = (_Float16)(C2EXP * a.y);
    hv[2] = (_Float16)(C2EXP * a.z); hv[3] = (_Float16)(C2EXP * a.w);
    hv[4] = (_Float16)(C2EXP * b.x); hv[5] = (_Float16)(C2EXP * b.y);
    hv[6] = (_Float16)(C2EXP * b.z); hv[7] = (_Float16)(C2EXP * b.w);
    *(half8*)(Pw + (size_t)copy * PW_COPY + (size_t)id * 8) = hv;
}

// Grid: 512 blocks x 512 thr (8 waves). Block owns 64 rows x all 2048 cols.
// wave w: rg=w>>2 (32-row group), colq=w&3 (4 concepts per 128-col chunk).
// Staging reads the XCD-local Pw copy (blockIdx%8): local-L2 hits.
// Pipeline: raw s_barrier + counted s_waitcnt vmcnt(4) -- loads issued one
// full chunk ahead are complete by their wait; NO vmcnt(0) drain mid-loop.
__global__ __attribute__((amdgpu_flat_work_group_size(512, 512),
                          amdgpu_waves_per_eu(4, 4)))
void mpcl_main(const float* __restrict__ V,        // (32768, 128) f32
               const int*   __restrict__ labels,   // (32768)
               const _Float16* __restrict__ Pw,    // packed P, 8 copies
               int* __restrict__ ws,               // [0]=gcnt ; +256B: partials
               float* __restrict__ out)
{
    __shared__ __align__(16) _Float16 Pst[2][2048 * 8];   // 2 x 32 KB
    __shared__ float sh_denom[64];
    __shared__ float sh_simpos[64];
    __shared__ float sh_fin[16];
    __shared__ int   sh_last;

    int*   gcnt = ws;
    float* part = (float*)((char*)ws + 256);

    const int tid  = threadIdx.x;
    const int lane = tid & 63;
    const int w    = tid >> 6;        // 0..7
    const int colq = w & 3;
    const int rg   = w >> 2;          // 0..1
    const int n    = lane & 15;
    const int q    = lane >> 4;
    const int rowbase = blockIdx.x * 64;

    if (tid < 64) { sh_denom[tid] = 0.0f; sh_simpos[tid] = 0.0f; }

    int lab = 0;
    if (tid < 64) lab = labels[rowbase + tid];    // prefetch early

    // XCD-local copy: main block b runs on XCD b%8 (round-robin dispatch),
    // reads the copy prep wrote from that same XCD.
    const _Float16* gbase = Pw + (size_t)(blockIdx.x & 7) * PW_COPY
                               + (size_t)(w * 256 + lane) * 8;

#define STAGE(CH, B) do {                                       \
    const _Float16* g_ = gbase + (size_t)(CH) * 16384;          \
    _Float16* l_ = &Pst[B][(w * 256) * 8];                      \
    GLD16(g_,        l_);                                       \
    GLD16(g_ +  512, l_ +  512);                                \
    GLD16(g_ + 1024, l_ + 1024);                                \
    GLD16(g_ + 1536, l_ + 1536);                                \
} while (0)

    // ---- V fragments (B operand), f16, register-resident (32 VGPR) ----
    half8 vh[2][4];
#pragma unroll
    for (int rf = 0; rf < 2; ++rf) {
        const float* vr = V + ((size_t)(rowbase + rg * 32 + rf * 16 + n) << 7) + q * 8;
#pragma unroll
        for (int c = 0; c < 4; ++c) {
            float4 x0 = *(const float4*)(vr + c * 32);
            float4 x1 = *(const float4*)(vr + c * 32 + 4);
            vh[rf][c][0] = (_Float16)x0.x; vh[rf][c][1] = (_Float16)x0.y;
            vh[rf][c][2] = (_Float16)x0.z; vh[rf][c][3] = (_Float16)x0.w;
            vh[rf][c][4] = (_Float16)x1.x; vh[rf][c][5] = (_Float16)x1.y;
            vh[rf][c][6] = (_Float16)x1.z; vh[rf][c][7] = (_Float16)x1.w;
        }
    }

    __syncthreads();   // sh_* init visible; (also drains vh loads, once)

    STAGE(0, 0);       // chunk 0 + 1 in flight (8 outstanding per wave)
    STAGE(1, 1);

    const int rowk0 = (rowbase + rg * 32 + n) & 255;        // positive concept, rf=0
    const int rowk1 = (rowbase + rg * 32 + 16 + n) & 255;   // rf=1
    const int aoff  = (colq * 512 + lane) * 8;              // half index of a1(c=0)

    float dn0 = 0.f, dn1 = 0.f;
    int cA = colq * 4 + q;

#pragma unroll 1
    for (int ch = 0; ch < CHUNKS; ++ch) {
        // wait for THIS chunk's 4 loads (the next chunk's 4 may stay in flight)
        if (ch < CHUNKS - 1) asm volatile("s_waitcnt vmcnt(4)" ::: "memory");
        else                 asm volatile("s_waitcnt vmcnt(0)" ::: "memory");
        __builtin_amdgcn_s_barrier();   // all waves' chunk-ch DMA visible

        const _Float16* base = &Pst[ch & 1][0];

        f32x4 acc1[2] = {{0.f,0.f,0.f,0.f},{0.f,0.f,0.f,0.f}};
        f32x4 acc2[2] = {{0.f,0.f,0.f,0.f},{0.f,0.f,0.f,0.f}};
#pragma unroll
        for (int c = 0; c < 4; ++c) {
            half8 a1 = *(const half8*)&base[aoff + c * 512];          // frag c
            half8 a2 = *(const half8*)&base[aoff + c * 512 + 2048];   // frag 4+c
            acc1[0] = __builtin_amdgcn_mfma_f32_16x16x32_f16(a1, vh[0][c], acc1[0], 0, 0, 0);
            acc1[1] = __builtin_amdgcn_mfma_f32_16x16x32_f16(a1, vh[1][c], acc1[1], 0, 0, 0);
            acc2[0] = __builtin_amdgcn_mfma_f32_16x16x32_f16(a2, vh[0][c], acc2[0], 0, 0, 0);
            acc2[1] = __builtin_amdgcn_mfma_f32_16x16x32_f16(a2, vh[1][c], acc2[1], 0, 0, 0);
        }

        // ---- epilogue: y = C2EXP*sim from MFMA; softmax-over-8 in-lane ----
#pragma unroll
        for (int rf = 0; rf < 2; ++rf) {
            float x0 = acc1[rf][0], x1 = acc1[rf][1], x2 = acc1[rf][2], x3 = acc1[rf][3];
            float x4 = acc2[rf][0], x5 = acc2[rf][1], x6 = acc2[rf][2], x7 = acc2[rf][3];
            float e0 = EXP2F(x0), e1 = EXP2F(x1), e2 = EXP2F(x2), e3 = EXP2F(x3);
            float e4 = EXP2F(x4), e5 = EXP2F(x5), e6 = EXP2F(x6), e7 = EXP2F(x7);
            float es = ((e0 + e1) + (e2 + e3)) + ((e4 + e5) + (e6 + e7));
            float ss = fmaf(e0, x0, fmaf(e1, x1, fmaf(e2, x2, e3 * x3)))
                     + fmaf(e4, x4, fmaf(e5, x5, fmaf(e6, x6, e7 * x7)));
            float simY = __fdividef(ss, es);          // = C2EXP * sim_c
            if (rf) dn1 += EXP2F(simY); else dn0 += EXP2F(simY);
            if (cA == (rf ? rowk1 : rowk0))
                sh_simpos[rg * 32 + rf * 16 + n] = simY;   // unique writer per row
        }
        cA += 16;

        __builtin_amdgcn_s_barrier();   // all waves done reading Pst[ch&1]
        if (ch + 2 < CHUNKS) STAGE(ch + 2, ch & 1);   // refill freed buffer
    }

    // ---- fold denominators over the 4 q-groups (distinct concepts) ----
#pragma unroll
    for (int rf = 0; rf < 2; ++rf) {
        float t = rf ? dn1 : dn0;
        t += swz16(t);
        t += __shfl_xor(t, 32);
        if (lane < 16)
            atomicAdd(&sh_denom[rg * 32 + rf * 16 + n], t);
    }
    __syncthreads();

    // ---- in-block loss over 64 rows ----
    // lp = log(denom) - LT*(sim_pos + margin) = log(denom) - ln2*simY - 1.0
    float s = 0.f, cc = 0.f;
    if (tid < 64) {
        float lp = logf(sh_denom[tid] + 1e-8f) - LN2 * sh_simpos[tid] - 1.0f;
        float mk = (lab == 1) ? 1.0f : 0.0f;
        s = lp * mk;
        cc = mk;
    }
#pragma unroll
    for (int off = 32; off >= 1; off >>= 1) {
        s  += __shfl_down(s, off);
        cc += __shfl_down(cc, off);
    }

    // ---- uncontended per-block partials + counter; last block finalizes ----
    if (tid == 0) {
        __hip_atomic_store(&part[2 * blockIdx.x],     s,  __ATOMIC_RELAXED, __HIP_MEMORY_SCOPE_AGENT);
        __hip_atomic_store(&part[2 * blockIdx.x + 1], cc, __ATOMIC_RELAXED, __HIP_MEMORY_SCOPE_AGENT);
        __threadfence();
        int g = __hip_atomic_fetch_add(gcnt, 1, __ATOMIC_ACQ_REL, __HIP_MEMORY_SCOPE_AGENT);
        sh_last = (g == NBLK - 1);
    }
    __syncthreads();
    if (sh_last) {
        float ts = 0.f, tc = 0.f;
        for (int i = tid; i < NBLK; i += 512) {
            ts += __hip_atomic_load(&part[2 * i],     __ATOMIC_RELAXED, __HIP_MEMORY_SCOPE_AGENT);
            tc += __hip_atomic_load(&part[2 * i + 1], __ATOMIC_RELAXED, __HIP_MEMORY_SCOPE_AGENT);
        }
#pragma unroll
        for (int off = 32; off >= 1; off >>= 1) {
            ts += __shfl_down(ts, off);
            tc += __shfl_down(tc, off);
        }
        if (lane == 0) { sh_fin[w] = ts; sh_fin[8 + w] = tc; }
        __syncthreads();
        if (tid == 0) {
            ts = 0.f; tc = 0.f;
#pragma unroll
            for (int i = 0; i < 8; ++i) { ts += sh_fin[i]; tc += sh_fin[8 + i]; }
            out[0] = (tc > 0.0f) ? (ts / tc) : ts;
        }
    }
}

extern "C" void kernel_launch(void* const* d_in, const int* in_sizes, int n_in,
                              void* d_out, int out_size, void* d_ws, size_t ws_size,
                              hipStream_t stream)
{
    const float* V      = (const float*)d_in[0];
    const int*   labels = (const int*)d_in[1];
    const float* P      = (const float*)d_in[2];
    float* out = (float*)d_out;
    int*   ws  = (int*)d_ws;
    _Float16* Pw = (_Float16*)((char*)d_ws + 16384);   // 8 x 512 KB packed P

    mpcl_prep<<<1024, 256, 0, stream>>>(P, Pw, ws);    // also zeroes gcnt
    mpcl_main<<<NBLK, 512, 0, stream>>>(V, labels, Pw, ws, out);
}